// Round 1
// baseline (223.236 us; speedup 1.0000x reference)
//
#include <hip/hip_runtime.h>
#include <math.h>

// SpectralPooling: x (4,32,64,64,64) f32 -> out (4,32,32,32,32) f32.
// out = A ⊗ A ⊗ A applied separably, A[i,d] = sum_{k<32} s32(k)cos(pi(2i+1)k/64) * s64(k)cos(pi(2d+1)k/128)
// (TRUNC==OUT_SIZE so crop+pad+IDCT collapses into one 32x64 matrix per axis.)

#define PI_D 3.14159265358979323846

// ---- build A[32][64] in double, store f32 ----
__global__ void build_A_kernel(float* __restrict__ A) {
    int t = threadIdx.x;
    for (int e = t; e < 2048; e += 256) {
        int i = e >> 6;   // output index (32)
        int d = e & 63;   // input index (64)
        double acc = 0.0;
        for (int k = 0; k < 32; ++k) {
            double s32 = (k == 0) ? sqrt(1.0 / 32.0) : sqrt(2.0 / 32.0);
            double s64 = (k == 0) ? sqrt(1.0 / 64.0) : sqrt(2.0 / 64.0);
            double c1 = cos(PI_D * (2.0 * i + 1.0) * (double)k / 64.0);
            double c2 = cos(PI_D * (2.0 * d + 1.0) * (double)k / 128.0);
            acc += s32 * c1 * s64 * c2;
        }
        A[e] = (float)acc;
    }
}

// ---- kernel 1: per (bc,d) slab, contract H then W: S[64][64] -> O[32][32] ----
// grid = 128*64 = 8192 blocks, 256 threads
__global__ __launch_bounds__(256) void k_hw(const float* __restrict__ x,
                                            const float* __restrict__ Ag,
                                            float* __restrict__ w1) {
    __shared__ float S[64 * 65];   // slab, padded
    __shared__ float T[32 * 65];   // after H-contraction, padded
    __shared__ float Al[32 * 64];  // A row-major (uniform broadcast reads)
    __shared__ float At[64 * 33];  // At[w][l] = A[l][w] (per-lane l reads, conflict-free)

    const int t = threadIdx.x;
    const int blk = blockIdx.x;

    // load A into LDS (both layouts)
    for (int e = t; e < 2048; e += 256) {
        float a = Ag[e];
        Al[e] = a;
        int l = e >> 6, w = e & 63;
        At[w * 33 + l] = a;
    }

    // load slab (contiguous 4096 floats) via float4
    const float4* src4 = (const float4*)(x + (size_t)blk * 4096);
    for (int e = t; e < 1024; e += 256) {
        float4 v = src4[e];
        int h = e >> 4, w4 = (e & 15) * 4;
        float* dst = &S[h * 65 + w4];
        dst[0] = v.x; dst[1] = v.y; dst[2] = v.z; dst[3] = v.w;
    }
    __syncthreads();

    // stage B: T[j][w] = sum_h A[j][h] * S[h][w];  w = t&63, group g=t>>6 handles j in [8g,8g+8)
    {
        const int w = t & 63, g = t >> 6;
        float acc[8] = {0.f, 0.f, 0.f, 0.f, 0.f, 0.f, 0.f, 0.f};
        for (int h = 0; h < 64; ++h) {
            float s = S[h * 65 + w];
            #pragma unroll
            for (int m = 0; m < 8; ++m)
                acc[m] += Al[(g * 8 + m) * 64 + h] * s;
        }
        #pragma unroll
        for (int m = 0; m < 8; ++m)
            T[(g * 8 + m) * 65 + w] = acc[m];
    }
    __syncthreads();

    // stage C: O[j][l] = sum_w T[j][w] * A[l][w];  l = t&31, q=t>>5 handles j in [4q,4q+4)
    {
        const int l = t & 31, q = t >> 5;
        float acc[4] = {0.f, 0.f, 0.f, 0.f};
        for (int w = 0; w < 64; ++w) {
            float a = At[w * 33 + l];
            #pragma unroll
            for (int r = 0; r < 4; ++r)
                acc[r] += T[(q * 4 + r) * 65 + w] * a;
        }
        float* dst = w1 + (size_t)blk * 1024;
        #pragma unroll
        for (int r = 0; r < 4; ++r)
            dst[(q * 4 + r) * 32 + l] = acc[r];
    }
}

// ---- kernel 2: contract D: out[bc][k][p] = sum_d A[k][d] * w1[bc][d][p], p in [0,1024) ----
// grid = 128 blocks, 256 threads, 4 p per thread
__global__ __launch_bounds__(256) void k_d(const float* __restrict__ w1,
                                           const float* __restrict__ Ag,
                                           float* __restrict__ out) {
    __shared__ float Al[32 * 64];
    const int t = threadIdx.x, bc = blockIdx.x;
    for (int e = t; e < 2048; e += 256) Al[e] = Ag[e];
    __syncthreads();

    const float* src = w1 + (size_t)bc * 64 * 1024;
    float acc[32][4];
    #pragma unroll
    for (int k = 0; k < 32; ++k)
        #pragma unroll
        for (int r = 0; r < 4; ++r) acc[k][r] = 0.f;

    for (int d = 0; d < 64; ++d) {
        const float* row = src + d * 1024;
        float v0 = row[t];
        float v1 = row[t + 256];
        float v2 = row[t + 512];
        float v3 = row[t + 768];
        #pragma unroll
        for (int k = 0; k < 32; ++k) {
            float a = Al[k * 64 + d];
            acc[k][0] += a * v0;
            acc[k][1] += a * v1;
            acc[k][2] += a * v2;
            acc[k][3] += a * v3;
        }
    }

    float* dst = out + (size_t)bc * 32 * 1024;
    #pragma unroll
    for (int k = 0; k < 32; ++k) {
        float* o = dst + k * 1024;
        o[t]       = acc[k][0];
        o[t + 256] = acc[k][1];
        o[t + 512] = acc[k][2];
        o[t + 768] = acc[k][3];
    }
}

extern "C" void kernel_launch(void* const* d_in, const int* in_sizes, int n_in,
                              void* d_out, int out_size, void* d_ws, size_t ws_size,
                              hipStream_t stream) {
    const float* x = (const float*)d_in[0];
    float* out = (float*)d_out;

    float* A  = (float*)d_ws;                       // 2048 floats (8 KiB)
    float* w1 = (float*)((char*)d_ws + 8192);       // 128*64*1024 floats (32 MiB)

    build_A_kernel<<<1, 256, 0, stream>>>(A);
    k_hw<<<8192, 256, 0, stream>>>(x, A, w1);
    k_d<<<128, 256, 0, stream>>>(w1, A, out);
}

// Round 2
// 117.854 us; speedup vs baseline: 1.8942x; 1.8942x over previous
//
#include <hip/hip_runtime.h>
#include <math.h>

// SpectralPooling: x (4,32,64,64,64) f32 -> out (4,32,32,32,32) f32.
// Separable: out = A (x)_D A (x)_H A (x)_W, with A[i,d] (32x64) the fused
// DCT64 -> crop32 -> IDCT32 matrix. We store At[d][i] (64x32, input-major)
// so every contraction reads a *column of A* = contiguous 32 floats, fetched
// wave-uniformly (s_load, SGPR operand to v_fmac -> no LDS traffic for A).

#define PI_F 3.14159265358979323846f

// ---- At[64][32]: At[d*32+i] = sum_k s32(k)s64(k)cos(pi(2i+1)k/64)cos(pi(2d+1)k/128)
// exact integer angle reduction (period 2pi -> mod 128 / mod 256), then cosf.
__global__ void build_At_kernel(float* __restrict__ At) {
    int e = blockIdx.x * 256 + threadIdx.x;
    if (e >= 2048) return;
    int d = e >> 5;
    int i = e & 31;
    const float s1 = sqrtf(1.0f / 32.0f), s2 = sqrtf(2.0f / 32.0f);
    const float t1 = sqrtf(1.0f / 64.0f), t2 = sqrtf(2.0f / 64.0f);
    float acc = 0.f;
    for (int k = 0; k < 32; ++k) {
        int n1 = ((2 * i + 1) * k) & 127;  // cos(pi*n1/64)
        int n2 = ((2 * d + 1) * k) & 255;  // cos(pi*n2/128)
        float c1 = cosf((float)n1 * (PI_F / 64.0f));
        float c2 = cosf((float)n2 * (PI_F / 128.0f));
        float sa = (k == 0) ? s1 : s2;
        float sb = (k == 0) ? t1 : t2;
        acc += sa * sb * c1 * c2;
    }
    At[e] = acc;
}

// ---- k_hw8: 8 slabs per block (512 threads, 8 waves). grid = 1024.
// Stage B (H-contract): wave = slab, lane = w. x read straight from global
//   (coalesced 256B/row), acc[j=0..31] in VGPRs, A column via s_load.
//   T[j][w] stored to LDS at [slab][j][w ^ j]  (XOR swizzle: conflict-free
//   for the lane=w write AND the lane=j transposed read).
// Stage C (W-contract): lane = (j, slab-parity), wave = (slab-pair, l-half).
//   Per w: 1 ds_read_b32 + 16 v_fmac with SGPR A column.
__global__ __launch_bounds__(512, 4) void k_hw8(const float* __restrict__ x,
                                                const float* __restrict__ At,
                                                float* __restrict__ w1) {
    __shared__ float T[8 * 32 * 64];  // 64 KiB: [slab][j][w ^ j]
    const int t = threadIdx.x;
    const int wave = t >> 6;
    const int lane = t & 63;
    const size_t blockSlab = (size_t)blockIdx.x * 8;

    // ---- stage B ----
    {
        const float* xs = x + (blockSlab + wave) * 4096 + lane;
        float acc[32];
        #pragma unroll
        for (int j = 0; j < 32; ++j) acc[j] = 0.f;
        #pragma unroll 8
        for (int h = 0; h < 64; ++h) {
            float s = xs[h * 64];
            const float* arow = At + h * 32;  // wave-uniform -> s_load
            #pragma unroll
            for (int j = 0; j < 32; ++j) acc[j] += arow[j] * s;
        }
        float* tb = T + wave * 2048;
        #pragma unroll
        for (int j = 0; j < 32; ++j)
            tb[j * 64 + (lane ^ j)] = acc[j];
    }
    __syncthreads();

    // ---- stage C ----
    {
        const int j = lane & 31, sl = lane >> 5;
        const int P = wave & 3, lh = wave >> 2;
        const int slab = 2 * P + sl;
        const float* tb = T + slab * 2048 + j * 64;
        float acc[16];
        #pragma unroll
        for (int l = 0; l < 16; ++l) acc[l] = 0.f;
        #pragma unroll 4
        for (int w = 0; w < 64; ++w) {
            float tv = tb[w ^ j];                      // conflict-free (swizzled)
            const float* arow = At + w * 32 + lh * 16; // wave-uniform -> s_load
            #pragma unroll
            for (int l = 0; l < 16; ++l) acc[l] += arow[l] * tv;
        }
        float4* dst = (float4*)(w1 + (blockSlab + slab) * 1024 + j * 32 + lh * 16);
        #pragma unroll
        for (int q = 0; q < 4; ++q)
            dst[q] = make_float4(acc[4 * q], acc[4 * q + 1], acc[4 * q + 2], acc[4 * q + 3]);
    }
}

// ---- k_d: D-contract. grid = 512 (bc x quarter), 256 threads, thread-per-p.
// out[bc][k][p] = sum_d At[d][k] * w1[bc][d][p]
__global__ __launch_bounds__(256, 4) void k_d(const float* __restrict__ w1,
                                              const float* __restrict__ At,
                                              float* __restrict__ out) {
    const int t = threadIdx.x;
    const int bc = blockIdx.x >> 2;
    const int q = blockIdx.x & 3;
    const int p = q * 256 + t;
    const float* src = w1 + (size_t)bc * 65536 + p;
    float acc[32];
    #pragma unroll
    for (int k = 0; k < 32; ++k) acc[k] = 0.f;
    #pragma unroll 4
    for (int d = 0; d < 64; ++d) {
        float v = src[d * 1024];                 // coalesced across lanes
        const float* arow = At + d * 32;         // wave-uniform -> s_load
        #pragma unroll
        for (int k = 0; k < 32; ++k) acc[k] += arow[k] * v;
    }
    float* dst = out + (size_t)bc * 32768 + p;
    #pragma unroll
    for (int k = 0; k < 32; ++k) dst[k * 1024] = acc[k];
}

extern "C" void kernel_launch(void* const* d_in, const int* in_sizes, int n_in,
                              void* d_out, int out_size, void* d_ws, size_t ws_size,
                              hipStream_t stream) {
    const float* x = (const float*)d_in[0];
    float* out = (float*)d_out;

    float* At = (float*)d_ws;                    // 2048 floats (8 KiB)
    float* w1 = (float*)((char*)d_ws + 8192);    // 128*64*1024 floats (32 MiB)

    build_At_kernel<<<8, 256, 0, stream>>>(At);
    k_hw8<<<1024, 512, 0, stream>>>(x, At, w1);
    k_d<<<512, 256, 0, stream>>>(w1, At, out);
}

// Round 3
// 100.747 us; speedup vs baseline: 2.2158x; 1.1698x over previous
//
#include <hip/hip_runtime.h>
#include <math.h>
#include <stdint.h>

// SpectralPooling: x (4,32,64,64,64) f32 -> out (4,32,32,32,32) f32.
// Separable: out[bc,k,j,l] = sum_{d,h,w} A[k,d]A[j,h]A[l,w] x[bc,d,h,w],
// A = (32x64) fused DCT64->crop32->IDCT32 matrix.
// k_hw (MFMA bf16): per slab (bc,d):  U[h][l] = sum_w X[h][w]*A[l][w]   (16 mfma)
//                                  O[j][l] = sum_h A[j][h]*U[h][l]      (8 mfma, via Ut in LDS)
// k_d (VALU f32):   out[bc,k,p] = sum_d A[k,d] * w1[bc,d,p]
//
// MFMA operand conventions used (mfma_f32_16x16x32_bf16):
//   A-op: lane m = lane&15, k = 8*(lane>>4)+jj (jj ascending, 8 contiguous bf16)
//   B-op: lane n = lane&15, same k map.  (Any consistent k-permutation cancels.)
//   C/D : col(n) = lane&15, row(m) = 4*(lane>>4)+reg   [HW-verified]

#define PI_F 3.14159265358979323846f

typedef __attribute__((ext_vector_type(4))) float f32x4;
typedef __attribute__((ext_vector_type(8))) short bf16x8;

union U16x8 { uint4 q; bf16x8 v; };

__device__ __forceinline__ unsigned short bf16r(float x) {
    union { float f; uint32_t u; } c; c.f = x;
    uint32_t r = (c.u + 0x7FFFu + ((c.u >> 16) & 1u)) >> 16;  // RNE
    return (unsigned short)r;
}

// ---- build At[64][32] f32 (for k_d) and F frag table (for k_hw) ----
// F[((tt*2+kt)*64+lane)*8+jj] = bf16(A[tt*16+(lane&15)][kt*32+8*(lane>>4)+jj])
__global__ __launch_bounds__(256) void build_tables(float* __restrict__ At,
                                                    unsigned short* __restrict__ F) {
    __shared__ float Ash[2048];  // A[i][d], row-major i*64+d
    const int t = threadIdx.x;
    const float s1 = sqrtf(1.0f / 32.0f), s2 = sqrtf(2.0f / 32.0f);
    const float t1 = sqrtf(1.0f / 64.0f), t2 = sqrtf(2.0f / 64.0f);
    for (int e = t; e < 2048; e += 256) {
        int i = e >> 6, d = e & 63;
        float acc = 0.f;
        for (int k = 0; k < 32; ++k) {
            int n1 = ((2 * i + 1) * k) & 127;   // cos(pi*n1/64)
            int n2 = ((2 * d + 1) * k) & 255;   // cos(pi*n2/128)
            float c1 = cosf((float)n1 * (PI_F / 64.0f));
            float c2 = cosf((float)n2 * (PI_F / 128.0f));
            acc += ((k == 0) ? s1 : s2) * ((k == 0) ? t1 : t2) * c1 * c2;
        }
        Ash[i * 64 + d] = acc;
        At[d * 32 + i] = acc;
    }
    __syncthreads();
    for (int e = t; e < 2048; e += 256) {
        int jj = e & 7, lane = (e >> 3) & 63, tk = e >> 9;
        int tt = tk >> 1, kt = tk & 1;
        int row = tt * 16 + (lane & 15);
        int col = kt * 32 + ((lane >> 4) << 3) + jj;
        F[e] = bf16r(Ash[row * 64 + col]);
    }
}

// ---- k_hw: 4 waves/block, one slab per wave, no __syncthreads ----
__global__ __launch_bounds__(256) void k_hw(const float* __restrict__ x,
                                            const unsigned short* __restrict__ F,
                                            float* __restrict__ w1) {
    __shared__ unsigned short Ut[4][2048];   // per-wave Ut[l][h] bf16, XOR-swizzled
    __shared__ float Ob[4][32 * 36];         // per-wave O[j][l] f32, padded rows (36)

    const int t = threadIdx.x;
    const int wv = t >> 6, ln = t & 63;
    const int lm = ln & 15, lg = ln >> 4;
    const size_t slab = (size_t)blockIdx.x * 4 + wv;

    // hoisted constant B-operand frags: Ff[nt][kt] = A[out-tile nt][in-tile kt]
    bf16x8 Ff[2][2];
    {
        const uint4* fp = (const uint4*)F;
        #pragma unroll
        for (int tt = 0; tt < 2; ++tt)
            #pragma unroll
            for (int kt = 0; kt < 2; ++kt) {
                U16x8 u; u.q = fp[(tt * 2 + kt) * 64 + ln];
                Ff[tt][kt] = u.v;
            }
    }

    // ---- stage B': U[h][l] = sum_w X[h][w] * A[l][w] ----
    const float* xs = x + slab * 4096;
    f32x4 accu[4][2];
    #pragma unroll
    for (int mt = 0; mt < 4; ++mt)
        #pragma unroll
        for (int nt = 0; nt < 2; ++nt)
            accu[mt][nt] = (f32x4){0.f, 0.f, 0.f, 0.f};

    #pragma unroll
    for (int mt = 0; mt < 4; ++mt) {
        #pragma unroll
        for (int kt = 0; kt < 2; ++kt) {
            const float4* p = (const float4*)(xs + (mt * 16 + lm) * 64 + kt * 32 + (lg << 3));
            float4 a = p[0], b = p[1];          // 8 consecutive w (f32)
            bf16x8 xf;
            xf[0] = (short)bf16r(a.x); xf[1] = (short)bf16r(a.y);
            xf[2] = (short)bf16r(a.z); xf[3] = (short)bf16r(a.w);
            xf[4] = (short)bf16r(b.x); xf[5] = (short)bf16r(b.y);
            xf[6] = (short)bf16r(b.z); xf[7] = (short)bf16r(b.w);
            #pragma unroll
            for (int nt = 0; nt < 2; ++nt)
                accu[mt][nt] = __builtin_amdgcn_mfma_f32_16x16x32_bf16(
                    xf, Ff[nt][kt], accu[mt][nt], 0, 0, 0);
        }
    }

    // ---- transpose U -> Ut[l][h] (bf16, XOR-swizzled), wave-private ----
    unsigned short* ut = Ut[wv];
    #pragma unroll
    for (int mt = 0; mt < 4; ++mt)
        #pragma unroll
        for (int nt = 0; nt < 2; ++nt) {
            int lo = nt * 16 + lm;               // Ut row (= l)
            int h0 = mt * 16 + (lg << 2);        // 4 consecutive h (regs 0..3)
            uint32_t w0 = (uint32_t)bf16r(accu[mt][nt][0]) |
                          ((uint32_t)bf16r(accu[mt][nt][1]) << 16);
            uint32_t w1v = (uint32_t)bf16r(accu[mt][nt][2]) |
                           ((uint32_t)bf16r(accu[mt][nt][3]) << 16);
            uint32_t byte = (uint32_t)(lo * 128 + 2 * h0);
            byte ^= (uint32_t)((lo & 7) << 4);   // bank swizzle
            *(uint2*)((char*)ut + byte) = make_uint2(w0, w1v);
        }
    __builtin_amdgcn_wave_barrier();

    // ---- stage C': O^T[l][j] = sum_h Ut[l][h] * A[j][h] ----
    f32x4 acco[2][2];
    #pragma unroll
    for (int mt = 0; mt < 2; ++mt)
        #pragma unroll
        for (int nt = 0; nt < 2; ++nt)
            acco[mt][nt] = (f32x4){0.f, 0.f, 0.f, 0.f};

    #pragma unroll
    for (int mt = 0; mt < 2; ++mt) {
        #pragma unroll
        for (int kt = 0; kt < 2; ++kt) {
            int lo = mt * 16 + lm;
            uint32_t byte = (uint32_t)(lo * 128 + kt * 64 + (lg << 4));
            byte ^= (uint32_t)((lo & 7) << 4);
            bf16x8 uf = *(const bf16x8*)((const char*)ut + byte);  // ds_read_b128
            #pragma unroll
            for (int nt = 0; nt < 2; ++nt)
                acco[mt][nt] = __builtin_amdgcn_mfma_f32_16x16x32_bf16(
                    uf, Ff[nt][kt], acco[mt][nt], 0, 0, 0);
        }
    }

    // ---- bounce O through LDS (transpose to [j][l]) and write coalesced ----
    float* ob = Ob[wv];
    #pragma unroll
    for (int mt = 0; mt < 2; ++mt)
        #pragma unroll
        for (int nt = 0; nt < 2; ++nt)
            #pragma unroll
            for (int r = 0; r < 4; ++r) {
                int lo = mt * 16 + (lg << 2) + r;  // l
                int j  = nt * 16 + lm;             // j
                ob[j * 36 + lo] = acco[mt][nt][r];
            }
    __builtin_amdgcn_wave_barrier();

    const int row = ln >> 1, half = ln & 1;
    const float4* obv = (const float4*)(ob + row * 36 + half * 16);
    float4 o0 = obv[0], o1 = obv[1], o2 = obv[2], o3 = obv[3];
    float4* dst = (float4*)(w1 + slab * 1024 + row * 32 + half * 16);
    dst[0] = o0; dst[1] = o1; dst[2] = o2; dst[3] = o3;
}

// ---- k_d: D-contract (unchanged from R2; it was effectively free) ----
__global__ __launch_bounds__(256, 4) void k_d(const float* __restrict__ w1,
                                              const float* __restrict__ At,
                                              float* __restrict__ out) {
    const int t = threadIdx.x;
    const int bc = blockIdx.x >> 2;
    const int q = blockIdx.x & 3;
    const int p = q * 256 + t;
    const float* src = w1 + (size_t)bc * 65536 + p;
    float acc[32];
    #pragma unroll
    for (int k = 0; k < 32; ++k) acc[k] = 0.f;
    #pragma unroll 4
    for (int d = 0; d < 64; ++d) {
        float v = src[d * 1024];
        const float* arow = At + d * 32;
        #pragma unroll
        for (int k = 0; k < 32; ++k) acc[k] += arow[k] * v;
    }
    float* dst = out + (size_t)bc * 32768 + p;
    #pragma unroll
    for (int k = 0; k < 32; ++k) dst[k * 1024] = acc[k];
}

extern "C" void kernel_launch(void* const* d_in, const int* in_sizes, int n_in,
                              void* d_out, int out_size, void* d_ws, size_t ws_size,
                              hipStream_t stream) {
    const float* x = (const float*)d_in[0];
    float* out = (float*)d_out;

    float* At          = (float*)d_ws;                        // 8 KiB
    unsigned short* F  = (unsigned short*)((char*)d_ws + 8192);  // 4 KiB
    float* w1          = (float*)((char*)d_ws + 16384);       // 32 MiB

    build_tables<<<1, 256, 0, stream>>>(At, F);
    k_hw<<<2048, 256, 0, stream>>>(x, F, w1);
    k_d<<<512, 256, 0, stream>>>(w1, At, out);
}

// Round 4
// 46.674 us; speedup vs baseline: 4.7829x; 2.1585x over previous
//
#include <hip/hip_runtime.h>
#include <math.h>
#include <stdint.h>

// SpectralPooling: x (4,32,64,64,64) f32 -> out (4,32,32,32,32) f32.
// Separable: out[bc,k,j,l] = sum_{d,h,w} A[k,d]A[j,h]A[l,w] x[bc,d,h,w],
// A = (32x64) fused DCT64->crop32->IDCT32 matrix.
// k_hw (MFMA bf16): per slab (bc,d):  U[h][l] = sum_w X[h][w]*A[l][w]
//                                    O[j][l] = sum_h A[j][h]*U[h][l]  -> w1 (bf16)
// k_d (VALU f32):   out[bc,k,p] = sum_d A[k,d] * w1[bc,d,p]
//
// MFMA operand conventions (mfma_f32_16x16x32_bf16), verified passing R3:
//   A-op: lane m = lane&15, k = 8*(lane>>4)+jj ; B-op same map (k-perm cancels)
//   C/D : col = lane&15, row = 4*(lane>>4)+reg

#define PI_F 3.14159265358979323846f

typedef __attribute__((ext_vector_type(4))) float f32x4;
typedef __attribute__((ext_vector_type(8))) short bf16x8;

union U16x8 { uint4 q; bf16x8 v; };

__device__ __forceinline__ unsigned short bf16r(float x) {
    union { float f; uint32_t u; } c; c.f = x;
    uint32_t r = (c.u + 0x7FFFu + ((c.u >> 16) & 1u)) >> 16;  // RNE
    return (unsigned short)r;
}

__device__ __forceinline__ float Aelem(int i, int d) {
    const float s1 = sqrtf(1.0f / 32.0f), s2 = sqrtf(2.0f / 32.0f);
    const float t1 = sqrtf(1.0f / 64.0f), t2 = sqrtf(2.0f / 64.0f);
    float acc = 0.f;
    for (int k = 0; k < 32; ++k) {
        int n1 = ((2 * i + 1) * k) & 127;   // cos(pi*n1/64)
        int n2 = ((2 * d + 1) * k) & 255;   // cos(pi*n2/128)
        float c1 = cosf((float)n1 * (PI_F / 64.0f));
        float c2 = cosf((float)n2 * (PI_F / 128.0f));
        acc += ((k == 0) ? s1 : s2) * ((k == 0) ? t1 : t2) * c1 * c2;
    }
    return acc;
}

// ---- tables: At[64][32] f32 (k_d) + F frag table bf16 (k_hw). 16 blocks. ----
__global__ __launch_bounds__(256) void build_tables(float* __restrict__ At,
                                                    unsigned short* __restrict__ F) {
    int e = blockIdx.x * 256 + threadIdx.x;
    if (e < 2048) {
        int d = e >> 5, i = e & 31;
        At[e] = Aelem(i, d);
    } else if (e < 4096) {
        int f = e - 2048;
        int jj = f & 7, lane = (f >> 3) & 63, tk = f >> 9;
        int tt = tk >> 1, kt = tk & 1;
        int row = tt * 16 + (lane & 15);
        int col = kt * 32 + ((lane >> 4) << 3) + jj;
        F[f] = bf16r(Aelem(row, col));
    }
}

// ---- k_hw: 4 waves/block, one slab per wave, no __syncthreads ----
__global__ __launch_bounds__(256) void k_hw(const float* __restrict__ x,
                                            const unsigned short* __restrict__ F,
                                            unsigned short* __restrict__ w1b) {
    __shared__ unsigned short Ut[4][2048];   // per-wave Ut[l][h] bf16, XOR-swizzled
    __shared__ float Ob[4][32 * 36];         // per-wave O[j][l] f32, padded rows

    const int t = threadIdx.x;
    const int wv = t >> 6, ln = t & 63;
    const int lm = ln & 15, lg = ln >> 4;
    const size_t slab = (size_t)blockIdx.x * 4 + wv;

    // hoisted constant B-operand frags: Ff[out-tile][in-tile]
    bf16x8 Ff[2][2];
    {
        const uint4* fp = (const uint4*)F;
        #pragma unroll
        for (int tt = 0; tt < 2; ++tt)
            #pragma unroll
            for (int kt = 0; kt < 2; ++kt) {
                U16x8 u; u.q = fp[(tt * 2 + kt) * 64 + ln];
                Ff[tt][kt] = u.v;
            }
    }

    // ---- stage B': U[h][l] = sum_w X[h][w] * A[l][w] ----
    const float* xs = x + slab * 4096;
    f32x4 accu[4][2];
    #pragma unroll
    for (int mt = 0; mt < 4; ++mt)
        #pragma unroll
        for (int nt = 0; nt < 2; ++nt)
            accu[mt][nt] = (f32x4){0.f, 0.f, 0.f, 0.f};

    #pragma unroll
    for (int mt = 0; mt < 4; ++mt) {
        #pragma unroll
        for (int kt = 0; kt < 2; ++kt) {
            const float4* p = (const float4*)(xs + (mt * 16 + lm) * 64 + kt * 32 + (lg << 3));
            float4 a = p[0], b = p[1];          // 8 consecutive w (f32)
            bf16x8 xf;
            xf[0] = (short)bf16r(a.x); xf[1] = (short)bf16r(a.y);
            xf[2] = (short)bf16r(a.z); xf[3] = (short)bf16r(a.w);
            xf[4] = (short)bf16r(b.x); xf[5] = (short)bf16r(b.y);
            xf[6] = (short)bf16r(b.z); xf[7] = (short)bf16r(b.w);
            #pragma unroll
            for (int nt = 0; nt < 2; ++nt)
                accu[mt][nt] = __builtin_amdgcn_mfma_f32_16x16x32_bf16(
                    xf, Ff[nt][kt], accu[mt][nt], 0, 0, 0);
        }
    }

    // ---- transpose U -> Ut[l][h] (bf16, XOR-swizzled), wave-private ----
    unsigned short* ut = Ut[wv];
    #pragma unroll
    for (int mt = 0; mt < 4; ++mt)
        #pragma unroll
        for (int nt = 0; nt < 2; ++nt) {
            int lo = nt * 16 + lm;               // Ut row (= l)
            int h0 = mt * 16 + (lg << 2);        // 4 consecutive h
            uint32_t w0 = (uint32_t)bf16r(accu[mt][nt][0]) |
                          ((uint32_t)bf16r(accu[mt][nt][1]) << 16);
            uint32_t w1v = (uint32_t)bf16r(accu[mt][nt][2]) |
                           ((uint32_t)bf16r(accu[mt][nt][3]) << 16);
            uint32_t byte = (uint32_t)(lo * 128 + 2 * h0);
            byte ^= (uint32_t)((lo & 7) << 4);   // bank swizzle
            *(uint2*)((char*)ut + byte) = make_uint2(w0, w1v);
        }
    __builtin_amdgcn_wave_barrier();

    // ---- stage C': O^T[l][j] = sum_h Ut[l][h] * A[j][h] ----
    f32x4 acco[2][2];
    #pragma unroll
    for (int mt = 0; mt < 2; ++mt)
        #pragma unroll
        for (int nt = 0; nt < 2; ++nt)
            acco[mt][nt] = (f32x4){0.f, 0.f, 0.f, 0.f};

    #pragma unroll
    for (int mt = 0; mt < 2; ++mt) {
        #pragma unroll
        for (int kt = 0; kt < 2; ++kt) {
            int lo = mt * 16 + lm;
            uint32_t byte = (uint32_t)(lo * 128 + kt * 64 + (lg << 4));
            byte ^= (uint32_t)((lo & 7) << 4);
            bf16x8 uf = *(const bf16x8*)((const char*)ut + byte);  // ds_read_b128
            #pragma unroll
            for (int nt = 0; nt < 2; ++nt)
                acco[mt][nt] = __builtin_amdgcn_mfma_f32_16x16x32_bf16(
                    uf, Ff[nt][kt], acco[mt][nt], 0, 0, 0);
        }
    }

    // ---- bounce O through LDS (transpose to [j][l]), write bf16 coalesced ----
    float* ob = Ob[wv];
    #pragma unroll
    for (int mt = 0; mt < 2; ++mt)
        #pragma unroll
        for (int nt = 0; nt < 2; ++nt)
            #pragma unroll
            for (int r = 0; r < 4; ++r) {
                int lo = mt * 16 + (lg << 2) + r;  // l
                int j  = nt * 16 + lm;             // j
                ob[j * 36 + lo] = acco[mt][nt][r];
            }
    __builtin_amdgcn_wave_barrier();

    const int row = ln >> 1, half = ln & 1;
    const float4* obv = (const float4*)(ob + row * 36 + half * 16);
    float4 o0 = obv[0], o1 = obv[1], o2 = obv[2], o3 = obv[3];
    uint4 q0, q1;
    q0.x = (uint32_t)bf16r(o0.x) | ((uint32_t)bf16r(o0.y) << 16);
    q0.y = (uint32_t)bf16r(o0.z) | ((uint32_t)bf16r(o0.w) << 16);
    q0.z = (uint32_t)bf16r(o1.x) | ((uint32_t)bf16r(o1.y) << 16);
    q0.w = (uint32_t)bf16r(o1.z) | ((uint32_t)bf16r(o1.w) << 16);
    q1.x = (uint32_t)bf16r(o2.x) | ((uint32_t)bf16r(o2.y) << 16);
    q1.y = (uint32_t)bf16r(o2.z) | ((uint32_t)bf16r(o2.w) << 16);
    q1.z = (uint32_t)bf16r(o3.x) | ((uint32_t)bf16r(o3.y) << 16);
    q1.w = (uint32_t)bf16r(o3.z) | ((uint32_t)bf16r(o3.w) << 16);
    uint4* dst = (uint4*)(w1b + slab * 1024 + row * 32 + half * 16);
    dst[0] = q0;
    dst[1] = q1;
}

// ---- k_d: D-contract. grid = 128 bc x 2 khalf x 4 pquarter = 1024 blocks ----
// out[bc][kh*16+kk][p] = sum_d At[d][kh*16+kk] * w1b[bc][d][p]
__global__ __launch_bounds__(256) void k_d(const unsigned short* __restrict__ w1b,
                                           const float* __restrict__ At,
                                           float* __restrict__ out) {
    const int t = threadIdx.x;
    const int bc = blockIdx.x >> 3;
    const int kh = (blockIdx.x >> 2) & 1;
    const int q  = blockIdx.x & 3;
    const int p  = q * 256 + t;
    const unsigned short* src = w1b + (size_t)bc * 65536 + p;
    float acc[16];
    #pragma unroll
    for (int k = 0; k < 16; ++k) acc[k] = 0.f;
    #pragma unroll 8
    for (int d = 0; d < 64; ++d) {
        uint32_t u = (uint32_t)src[d * 1024];
        float v = __uint_as_float(u << 16);       // bf16 -> f32
        const float* arow = At + d * 32 + kh * 16;  // wave-uniform -> s_load
        #pragma unroll
        for (int k = 0; k < 16; ++k) acc[k] += arow[k] * v;
    }
    float* dst = out + (size_t)bc * 32768 + (size_t)kh * 16384 + p;
    #pragma unroll
    for (int k = 0; k < 16; ++k) dst[k * 1024] = acc[k];
}

extern "C" void kernel_launch(void* const* d_in, const int* in_sizes, int n_in,
                              void* d_out, int out_size, void* d_ws, size_t ws_size,
                              hipStream_t stream) {
    const float* x = (const float*)d_in[0];
    float* out = (float*)d_out;

    float* At          = (float*)d_ws;                            // 8 KiB
    unsigned short* F  = (unsigned short*)((char*)d_ws + 8192);   // 4 KiB
    unsigned short* w1b = (unsigned short*)((char*)d_ws + 16384); // 16 MiB (bf16)

    build_tables<<<16, 256, 0, stream>>>(At, F);
    k_hw<<<2048, 256, 0, stream>>>(x, F, w1b);
    k_d<<<1024, 256, 0, stream>>>(w1b, At, out);
}